// Round 2
// baseline (483.821 us; speedup 1.0000x reference)
//
#include <hip/hip_runtime.h>
#include <hip/hip_bf16.h>
#include <stdint.h>

#define B_DIM   8192
#define IN_DIM  4096
#define OUT_DIM 4096
#define BSZ     64
#define NBR_    64
#define BPR_    16
#define KTOT    1024   // BPR_*BSZ
#define MT      256    // batch tile (4 waves x 64 rows)
#define BKK     32     // K per MFMA step

typedef __attribute__((ext_vector_type(4))) float  floatx4;
typedef __attribute__((ext_vector_type(8))) short  shortx8;  // 8 bf16
typedef __attribute__((ext_vector_type(4))) float  fragc;    // 4 fp32 acc

__device__ __forceinline__ unsigned short f2bf(float f) {
  __bf16 b = (__bf16)f;  // RTNE hardware cvt
  return __builtin_bit_cast(unsigned short, b);
}

// ---------------- fp32 -> bf16 conversion ----------------------------------
__global__ __launch_bounds__(256) void cvt_kernel(const float* __restrict__ src,
                                                  unsigned short* __restrict__ dst,
                                                  int n8) {
  const int stride = gridDim.x * blockDim.x;
  for (int i = blockIdx.x * blockDim.x + threadIdx.x; i < n8; i += stride) {
    floatx4 a = ((const floatx4*)src)[2 * i];
    floatx4 b = ((const floatx4*)src)[2 * i + 1];
    uint4 o;
    o.x = (unsigned int)f2bf(a.x) | ((unsigned int)f2bf(a.y) << 16);
    o.y = (unsigned int)f2bf(a.z) | ((unsigned int)f2bf(a.w) << 16);
    o.z = (unsigned int)f2bf(b.x) | ((unsigned int)f2bf(b.y) << 16);
    o.w = (unsigned int)f2bf(b.z) | ((unsigned int)f2bf(b.w) << 16);
    ((uint4*)dst)[i] = o;
  }
}

// ---------------- LDS-free, barrier-free block-sparse GEMM -----------------
// Block = 4 waves. Wave tile = 64 rows x 64 cols (one block-row r), as a 4x4
// grid of 16x16x32 bf16 MFMAs. Fragments loaded straight global->VGPR
// (16B/lane, 4 lanes cover each 64B row chunk). Register double-buffered:
// loads for step k+1 issue before MFMAs of step k, no __syncthreads anywhere.
__global__ __launch_bounds__(256)
void bsr_gemm(const unsigned short* __restrict__ xb,
              const unsigned short* __restrict__ vb,
              const float* __restrict__ bias, const int* __restrict__ colidx,
              float* __restrict__ out) {
  const int r  = blockIdx.x;        // block-row 0..63
  const int m0 = blockIdx.y * MT;   // batch tile base
  const int tid  = threadIdx.x;
  const int wave = tid >> 6;
  const int lane = tid & 63;
  const int l16  = lane & 15;
  const int quad = lane >> 4;

  // uniform -> SGPRs
  int cidx[BPR_];
  #pragma unroll
  for (int j = 0; j < BPR_; ++j) cidx[j] = colidx[r * BPR_ + j];

  // per-lane base pointers
  const unsigned short* xrow = xb + (size_t)(m0 + wave * 64 + l16) * IN_DIM + quad * 8;
  const unsigned short* vblk = vb + ((size_t)(r * BPR_) * BSZ + l16) * BSZ + quad * 8;

  fragc acc[4][4] = {};
  shortx8 a0[4], b0[4], a1[4], b1[4];

#define LD(ks, af, bf)                                                        \
  {                                                                           \
    const int jb_ = (ks) >> 1, kb0_ = ((ks) & 1) * BKK;                       \
    const unsigned short* ap = xrow + cidx[jb_] * BSZ + kb0_;                 \
    _Pragma("unroll")                                                         \
    for (int mi = 0; mi < 4; ++mi)                                            \
      af[mi] = *(const shortx8*)(ap + (size_t)mi * 16 * IN_DIM);              \
    const unsigned short* bp = vblk + (size_t)jb_ * BSZ * BSZ + kb0_;         \
    _Pragma("unroll")                                                         \
    for (int ni = 0; ni < 4; ++ni)                                            \
      bf[ni] = *(const shortx8*)(bp + ni * 16 * BSZ);                         \
  }

#define MM(af, bf)                                                            \
  {                                                                           \
    _Pragma("unroll")                                                         \
    for (int mi = 0; mi < 4; ++mi) {                                          \
      _Pragma("unroll")                                                       \
      for (int ni = 0; ni < 4; ++ni)                                          \
        acc[mi][ni] = __builtin_amdgcn_mfma_f32_16x16x32_bf16(af[mi], bf[ni], \
                                                              acc[mi][ni],    \
                                                              0, 0, 0);       \
    }                                                                         \
  }

  LD(0, a0, b0);
  #pragma unroll
  for (int ks = 0; ks < KTOT / BKK; ks += 2) {
    LD(ks + 1, a1, b1);
    MM(a0, b0);
    if (ks + 2 < KTOT / BKK) LD(ks + 2, a0, b0);
    MM(a1, b1);
  }
#undef LD
#undef MM

  // epilogue: C/D layout col=lane&15, row=quad*4+reg (verified)
  #pragma unroll
  for (int ni = 0; ni < 4; ++ni) {
    const int col = r * BSZ + ni * 16 + l16;
    const float bv = bias[col];
    #pragma unroll
    for (int mi = 0; mi < 4; ++mi) {
      #pragma unroll
      for (int reg = 0; reg < 4; ++reg) {
        const int row = m0 + wave * 64 + mi * 16 + quad * 4 + reg;
        out[(size_t)row * OUT_DIM + col] = acc[mi][ni][reg] + bv;
      }
    }
  }
}

// ---------------- correctness-only fallback (no workspace) -----------------
__global__ __launch_bounds__(256)
void bsr_naive(const float* __restrict__ x, const float* __restrict__ v,
               const float* __restrict__ bias, const int* __restrict__ colidx,
               float* __restrict__ out) {
  const size_t gid = (size_t)blockIdx.x * blockDim.x + threadIdx.x;
  if (gid >= (size_t)B_DIM * OUT_DIM) return;
  const int b = gid / OUT_DIM;
  const int oc = gid % OUT_DIM;
  const int rr = oc / BSZ, o = oc % BSZ;
  float s = bias[oc];
  for (int j = 0; j < BPR_; ++j) {
    const int c = colidx[rr * BPR_ + j];
    const float* xp = x + (size_t)b * IN_DIM + c * BSZ;
    const float* vp = v + ((size_t)(rr * BPR_ + j) * BSZ + o) * BSZ;
    for (int k = 0; k < BSZ; ++k) s += vp[k] * xp[k];
  }
  out[gid] = s;
}

extern "C" void kernel_launch(void* const* d_in, const int* in_sizes, int n_in,
                              void* d_out, int out_size, void* d_ws, size_t ws_size,
                              hipStream_t stream) {
  const float* x    = (const float*)d_in[0];
  const float* vals = (const float*)d_in[1];
  const float* bias = (const float*)d_in[2];
  const int*   cols = (const int*)d_in[3];
  float* out = (float*)d_out;

  const size_t x_elems = (size_t)B_DIM * IN_DIM;
  const size_t v_elems = (size_t)NBR_ * BPR_ * BSZ * BSZ;
  const size_t xb_bytes = x_elems * sizeof(unsigned short);
  const size_t vb_bytes = v_elems * sizeof(unsigned short);

  if (ws_size >= xb_bytes + vb_bytes) {
    unsigned short* xbp = (unsigned short*)d_ws;
    unsigned short* vbp = (unsigned short*)((char*)d_ws + xb_bytes);
    cvt_kernel<<<dim3(8192), dim3(256), 0, stream>>>(x, xbp, (int)(x_elems / 8));
    cvt_kernel<<<dim3(2048), dim3(256), 0, stream>>>(vals, vbp, (int)(v_elems / 8));
    dim3 grid(NBR_, B_DIM / MT);  // r fastest: blocks of one batch tile co-dispatch
    bsr_gemm<<<grid, dim3(256), 0, stream>>>(xbp, vbp, bias, cols, out);
  } else {
    const size_t n = (size_t)B_DIM * OUT_DIM;
    bsr_naive<<<dim3((unsigned)((n + 255) / 256)), dim3(256), 0, stream>>>(
        x, vals, bias, cols, out);
  }
}

// Round 3
// 398.990 us; speedup vs baseline: 1.2126x; 1.2126x over previous
//
#include <hip/hip_runtime.h>
#include <hip/hip_bf16.h>
#include <stdint.h>

#define B_DIM   8192
#define IN_DIM  4096
#define OUT_DIM 4096
#define BSZ     64
#define NBR_    64
#define BPR_    16
#define KTOT    1024
#define MT      256
#define BKK     32
#define NSTEP   (KTOT / BKK)   // 32

typedef __attribute__((ext_vector_type(4))) float  floatx4;
typedef __attribute__((ext_vector_type(8))) short  shortx8;  // 8 bf16
typedef __attribute__((ext_vector_type(4))) float  fragc;    // 4 fp32 acc

static __device__ __forceinline__ unsigned short f2bf(float f) {
  __bf16 b = (__bf16)f;  // RTNE hardware cvt
  return __builtin_bit_cast(unsigned short, b);
}

__device__ __forceinline__ void gload_lds16(const void* g, void* l) {
  // 16B/lane, LDS dest = wave-uniform base + lane*16
  __builtin_amdgcn_global_load_lds(
      (const __attribute__((address_space(1))) unsigned int*)g,
      (__attribute__((address_space(3))) unsigned int*)l, 16, 0, 0);
}

// ---------------- fused fp32 -> bf16 conversion (x and values) -------------
__global__ __launch_bounds__(256)
void cvt2_kernel(const float* __restrict__ x, const float* __restrict__ v,
                 unsigned short* __restrict__ xb, unsigned short* __restrict__ vb,
                 int xn8, int tn8) {
  const int stride = gridDim.x * blockDim.x;
  for (int i = blockIdx.x * blockDim.x + threadIdx.x; i < tn8; i += stride) {
    const float* src; unsigned short* dst; int idx;
    if (i < xn8) { src = x; dst = xb; idx = i; }
    else         { src = v; dst = vb; idx = i - xn8; }
    floatx4 a = __builtin_nontemporal_load(((const floatx4*)src) + 2 * idx);
    floatx4 b = __builtin_nontemporal_load(((const floatx4*)src) + 2 * idx + 1);
    uint4 o;
    o.x = (unsigned int)f2bf(a.x) | ((unsigned int)f2bf(a.y) << 16);
    o.y = (unsigned int)f2bf(a.z) | ((unsigned int)f2bf(a.w) << 16);
    o.z = (unsigned int)f2bf(b.x) | ((unsigned int)f2bf(b.y) << 16);
    o.w = (unsigned int)f2bf(b.z) | ((unsigned int)f2bf(b.w) << 16);
    ((uint4*)dst)[idx] = o;
  }
}

// ---------------- block-sparse GEMM, dbuf LDS + manual vmcnt ---------------
// Block = 4 waves, tile 256 rows x 64 cols (one block-row r). Wave = 64x64 via
// 4x4 of 16x16x32 bf16 MFMA. Staging via global_load_lds w=16. Double-buffered
// LDS (separate __shared__ objects so LDS-DMA alias tracking disambiguates),
// raw s_barrier + manual vmcnt(0): wait(stage k) -> barrier -> issue stage(k+1)
// -> compute(k). XOR chunk swizzle kills the 8-way ds_read_b128 bank conflict.
__global__ __launch_bounds__(256, 4)
void bsr_gemm(const unsigned short* __restrict__ xb,
              const unsigned short* __restrict__ vb,
              const float* __restrict__ bias, const int* __restrict__ colidx,
              float* __restrict__ out) {
  const int r  = blockIdx.x;        // block-row 0..63
  const int m0 = blockIdx.y * MT;   // batch tile base
  const int tid  = threadIdx.x;
  const int wave = tid >> 6;
  const int lane = tid & 63;
  const int l16  = lane & 15;
  const int quad = lane >> 4;
  const int sub  = lane >> 2;       // staging row within 16-row chunk
  const int slot = lane & 3;        // staging 16B slot within 64B row
  const int gsw  = slot ^ ((sub >> 1) & 3);  // which global chunk lane stages
  const int csw  = quad ^ ((l16 >> 1) & 3);  // which LDS slot lane reads

  __shared__ __align__(16) unsigned short As0[MT * BKK];
  __shared__ __align__(16) unsigned short As1[MT * BKK];
  __shared__ __align__(16) unsigned short Bs0[BSZ * BKK];
  __shared__ __align__(16) unsigned short Bs1[BSZ * BKK];

  int cidx[BPR_];
  #pragma unroll
  for (int j = 0; j < BPR_; ++j)
    cidx[j] = __builtin_amdgcn_readfirstlane(colidx[r * BPR_ + j]);

  // per-lane staging source bases (shorts)
  const unsigned short* gA =
      xb + (size_t)(m0 + wave * 64 + sub) * IN_DIM + gsw * 8;
  const unsigned short* gB =
      vb + ((size_t)(r * BPR_) * BSZ + wave * 16 + sub) * BSZ + gsw * 8;

  // per-lane LDS read offsets (shorts)
  const int aoff = (wave * 64 + l16) * BKK + csw * 8;
  const int boff = l16 * BKK + csw * 8;

  fragc acc[4][4] = {};

#define STAGE(k, As, Bs)                                                      \
  {                                                                           \
    const int jb_ = (k) >> 1, kb0_ = ((k) & 1) * BKK;                         \
    const int colo_ = cidx[jb_] * BSZ + kb0_;                                 \
    _Pragma("unroll")                                                         \
    for (int i_ = 0; i_ < 4; ++i_)                                            \
      gload_lds16(gA + (size_t)i_ * 16 * IN_DIM + colo_,                      \
                  &As[(wave * 64 + i_ * 16) * BKK]);                          \
    gload_lds16(gB + (size_t)jb_ * BSZ * BSZ + kb0_,                          \
                &Bs[(wave * 16) * BKK]);                                      \
  }

#define COMP(As, Bs)                                                          \
  {                                                                           \
    shortx8 af_[4], bf_[4];                                                   \
    _Pragma("unroll")                                                         \
    for (int mi = 0; mi < 4; ++mi)                                            \
      af_[mi] = *(const shortx8*)&As[aoff + mi * 16 * BKK];                   \
    _Pragma("unroll")                                                         \
    for (int ni = 0; ni < 4; ++ni)                                            \
      bf_[ni] = *(const shortx8*)&Bs[boff + ni * 16 * BKK];                   \
    _Pragma("unroll")                                                         \
    for (int mi = 0; mi < 4; ++mi) {                                          \
      _Pragma("unroll")                                                       \
      for (int ni = 0; ni < 4; ++ni)                                          \
        acc[mi][ni] = __builtin_amdgcn_mfma_f32_16x16x32_bf16(                \
            af_[mi], bf_[ni], acc[mi][ni], 0, 0, 0);                          \
    }                                                                         \
  }

  // wait own stage loads -> barrier -> issue next stage -> compute current
#define SYNC()                                                                \
  asm volatile("s_waitcnt vmcnt(0)" ::: "memory");                            \
  __builtin_amdgcn_s_barrier();                                               \
  asm volatile("" ::: "memory");

  STAGE(0, As0, Bs0);
  #pragma unroll
  for (int k = 0; k < NSTEP; k += 2) {
    SYNC();
    STAGE(k + 1, As1, Bs1);
    COMP(As0, Bs0);
    SYNC();
    if (k + 2 < NSTEP) STAGE(k + 2, As0, Bs0);
    COMP(As1, Bs1);
  }
#undef STAGE
#undef COMP
#undef SYNC

  // epilogue: C/D layout col=lane&15, row=quad*4+reg (verified)
  #pragma unroll
  for (int ni = 0; ni < 4; ++ni) {
    const int col = r * BSZ + ni * 16 + l16;
    const float bv = bias[col];
    #pragma unroll
    for (int mi = 0; mi < 4; ++mi) {
      #pragma unroll
      for (int reg = 0; reg < 4; ++reg) {
        const int row = m0 + wave * 64 + mi * 16 + quad * 4 + reg;
        out[(size_t)row * OUT_DIM + col] = acc[mi][ni][reg] + bv;
      }
    }
  }
}

// ---------------- correctness-only fallback (no workspace) -----------------
__global__ __launch_bounds__(256)
void bsr_naive(const float* __restrict__ x, const float* __restrict__ v,
               const float* __restrict__ bias, const int* __restrict__ colidx,
               float* __restrict__ out) {
  const size_t gid = (size_t)blockIdx.x * blockDim.x + threadIdx.x;
  if (gid >= (size_t)B_DIM * OUT_DIM) return;
  const int b = gid / OUT_DIM;
  const int oc = gid % OUT_DIM;
  const int rr = oc / BSZ, o = oc % BSZ;
  float s = bias[oc];
  for (int j = 0; j < BPR_; ++j) {
    const int c = colidx[rr * BPR_ + j];
    const float* xp = x + (size_t)b * IN_DIM + c * BSZ;
    const float* vp = v + ((size_t)(rr * BPR_ + j) * BSZ + o) * BSZ;
    for (int k = 0; k < BSZ; ++k) s += vp[k] * xp[k];
  }
  out[gid] = s;
}

extern "C" void kernel_launch(void* const* d_in, const int* in_sizes, int n_in,
                              void* d_out, int out_size, void* d_ws, size_t ws_size,
                              hipStream_t stream) {
  const float* x    = (const float*)d_in[0];
  const float* vals = (const float*)d_in[1];
  const float* bias = (const float*)d_in[2];
  const int*   cols = (const int*)d_in[3];
  float* out = (float*)d_out;

  const size_t x_elems = (size_t)B_DIM * IN_DIM;
  const size_t v_elems = (size_t)NBR_ * BPR_ * BSZ * BSZ;
  const size_t xb_bytes = x_elems * sizeof(unsigned short);
  const size_t vb_bytes = v_elems * sizeof(unsigned short);

  if (ws_size >= xb_bytes + vb_bytes) {
    unsigned short* xbp = (unsigned short*)d_ws;
    unsigned short* vbp = (unsigned short*)((char*)d_ws + xb_bytes);
    const int xn8 = (int)(x_elems / 8);
    const int tn8 = (int)((x_elems + v_elems) / 8);
    cvt2_kernel<<<dim3(9216), dim3(256), 0, stream>>>(x, vals, xbp, vbp, xn8, tn8);
    dim3 grid(NBR_, B_DIM / MT);  // r fastest: same-mtile blocks co-dispatch
    bsr_gemm<<<grid, dim3(256), 0, stream>>>(xbp, vbp, bias, cols, out);
  } else {
    const size_t n = (size_t)B_DIM * OUT_DIM;
    bsr_naive<<<dim3((unsigned)((n + 255) / 256)), dim3(256), 0, stream>>>(
        x, vals, bias, cols, out);
  }
}